// Round 1
// baseline (507.606 us; speedup 1.0000x reference)
//
#include <hip/hip_runtime.h>

#define B_ 8
#define N_ 20000
#define M_ 1024
#define C_ 128
#define S_ 64
#define NCH_ 131   // 3 + C

__global__ __launch_bounds__(256) void qg_kernel(
    const float* __restrict__ xyz,       // (B, N, 3)
    const float* __restrict__ new_xyz,   // (B, M, 3)
    const float* __restrict__ features,  // (B, C, N)
    float* __restrict__ out)             // [B*131*M*S floats] ++ [B*M*S floats (idx)]
{
    const int bm = blockIdx.x;           // b*M + m
    const int b  = bm >> 10;             // M_ == 1024
    const int m  = bm & (M_ - 1);
    const int tid = threadIdx.x;

    __shared__ int s_idx[S_];

    if (tid < 64) {
        const int lane = tid;
        const float cx = new_xyz[bm * 3 + 0];
        const float cy = new_xyz[bm * 3 + 1];
        const float cz = new_xyz[bm * 3 + 2];
        const float r2 = (float)(0.3 * 0.3);   // exact f32 of python RADIUS^2
        const float* xb = xyz + (size_t)b * N_ * 3;

        int cnt = 0;
        for (int base = 0; base < N_; base += 64) {
            const int n = base + lane;
            bool valid = false;
            if (n < N_) {
                // match numpy f32 rounding exactly: no FMA contraction
                const float dx = __fadd_rn(xb[n * 3 + 0], -cx);
                const float dy = __fadd_rn(xb[n * 3 + 1], -cy);
                const float dz = __fadd_rn(xb[n * 3 + 2], -cz);
                const float d2 = __fadd_rn(
                    __fadd_rn(__fmul_rn(dx, dx), __fmul_rn(dy, dy)),
                    __fmul_rn(dz, dz));
                valid = d2 < r2;
            }
            const unsigned long long mk = __ballot(valid);
            if (valid) {
                const int pos = cnt + __popcll(mk & ((1ull << lane) - 1ull));
                if (pos < S_) s_idx[pos] = n;
            }
            cnt += __popcll(mk);
            if (cnt >= S_) break;   // wave-uniform
        }
        const int c = cnt < S_ ? cnt : S_;
        // LDS ops within a wave complete in order; cross-lane read is safe here
        const int first = (c > 0) ? s_idx[0] : 0;
        if (lane >= c) s_idx[lane] = first;

        // idx output, written as float (whole d_out is read back as f32)
        float* out_idx = out + (size_t)B_ * NCH_ * M_ * S_;
        out_idx[(size_t)bm * S_ + lane] = (float)s_idx[lane];
    }
    __syncthreads();

    // grouped relative xyz -> channels 0..2
    if (tid < 3 * S_) {
        const int ch = tid >> 6;     // 0..2
        const int s  = tid & 63;
        const int n  = s_idx[s];
        const float v = (xyz[((size_t)b * N_ + n) * 3 + ch] - new_xyz[bm * 3 + ch]) / 0.3f;
        out[(((size_t)b * NCH_ + ch) * M_ + m) * S_ + s] = v;
    }

    // feature gather -> channels 3..130
    const int s  = tid & 63;
    const int cq = tid >> 6;         // 0..3 (wave id)
    const int n  = s_idx[s];
    const float* fb = features + (size_t)b * C_ * N_;
    float* ob = out + (((size_t)b * NCH_ + 3) * M_ + m) * S_ + s;
    for (int ch = cq; ch < C_; ch += 4) {
        ob[(size_t)ch * (M_ * S_)] = fb[(size_t)ch * N_ + n];
    }
}

extern "C" void kernel_launch(void* const* d_in, const int* in_sizes, int n_in,
                              void* d_out, int out_size, void* d_ws, size_t ws_size,
                              hipStream_t stream) {
    const float* xyz      = (const float*)d_in[0];
    const float* new_xyz  = (const float*)d_in[1];
    // d_in[2] = batch_distances, d_in[3] = inds : acceleration hints only, unused
    const float* features = (const float*)d_in[4];
    float* out = (float*)d_out;

    qg_kernel<<<B_ * M_, 256, 0, stream>>>(xyz, new_xyz, features, out);
}

// Round 2
// 243.459 us; speedup vs baseline: 2.0850x; 2.0850x over previous
//
#include <hip/hip_runtime.h>

#define B_ 8
#define N_ 20000
#define M_ 1024
#define C_ 128
#define S_ 64
#define NCH_ 131   // 3 + C

// ---------------- Phase 1: ball query (1 wave per center, 4 centers/block) ---
__global__ __launch_bounds__(256) void query_kernel(
    const float* __restrict__ xyz,       // (B, N, 3)
    const float* __restrict__ new_xyz,   // (B, M, 3)
    float* __restrict__ out)             // idx region at offset B*NCH*M*S
{
    const int wid  = threadIdx.x >> 6;
    const int lane = threadIdx.x & 63;
    const int bm   = blockIdx.x * 4 + wid;
    const int b    = bm >> 10;

    __shared__ int s_idx[4][S_];

    const float cx = new_xyz[bm * 3 + 0];
    const float cy = new_xyz[bm * 3 + 1];
    const float cz = new_xyz[bm * 3 + 2];
    const float r2 = (float)(0.3 * 0.3);
    const float* xb = xyz + (size_t)b * N_ * 3;

    int cnt = 0;
    for (int base = 0; base < N_; base += 64) {
        const int n = base + lane;
        bool valid = false;
        if (n < N_) {
            // match numpy f32 rounding exactly: no FMA contraction
            const float dx = __fadd_rn(xb[n * 3 + 0], -cx);
            const float dy = __fadd_rn(xb[n * 3 + 1], -cy);
            const float dz = __fadd_rn(xb[n * 3 + 2], -cz);
            const float d2 = __fadd_rn(
                __fadd_rn(__fmul_rn(dx, dx), __fmul_rn(dy, dy)),
                __fmul_rn(dz, dz));
            valid = d2 < r2;
        }
        const unsigned long long mk = __ballot(valid);
        if (valid) {
            const int pos = cnt + __popcll(mk & ((1ull << lane) - 1ull));
            if (pos < S_) s_idx[wid][pos] = n;
        }
        cnt += __popcll(mk);
        if (cnt >= S_) break;   // wave-uniform
    }
    const int c = cnt < S_ ? cnt : S_;
    const int first = (c > 0) ? s_idx[wid][0] : 0;
    if (lane >= c) s_idx[wid][lane] = first;

    float* out_idx = out + (size_t)B_ * NCH_ * M_ * S_;
    out_idx[(size_t)bm * S_ + lane] = (float)s_idx[wid][lane];
}

// ---------------- Phase 2: features (B,C,N) -> ws (B,N,C), tiled transpose ---
__global__ __launch_bounds__(256) void transpose_kernel(
    const float* __restrict__ features,  // (B, C, N)
    float* __restrict__ ft)              // (B, N, C)
{
    __shared__ float tile[32][33];
    const int b  = blockIdx.z;
    const int c0 = blockIdx.y * 32;
    const int n0 = blockIdx.x * 32;
    const int tx = threadIdx.x;          // 0..31
    const int ty = threadIdx.y;          // 0..7

    const float* fb = features + (size_t)b * C_ * N_;
    float* tb = ft + (size_t)b * N_ * C_;

#pragma unroll
    for (int j = 0; j < 4; ++j) {
        const int c = c0 + ty + 8 * j;
        tile[ty + 8 * j][tx] = fb[(size_t)c * N_ + (n0 + tx)];
    }
    __syncthreads();
#pragma unroll
    for (int j = 0; j < 4; ++j) {
        const int n = n0 + ty + 8 * j;
        tb[(size_t)n * C_ + (c0 + tx)] = tile[tx][ty + 8 * j];
    }
}

// ---------------- Phase 3: grouped xyz + feature gather (1 block per center) -
__global__ __launch_bounds__(256) void gather_kernel(
    const float* __restrict__ xyz,       // (B, N, 3)
    const float* __restrict__ new_xyz,   // (B, M, 3)
    const float* __restrict__ ft,        // (B, N, C) transposed features
    float* __restrict__ out)
{
    const int bm = blockIdx.x;
    const int b  = bm >> 10;
    const int m  = bm & (M_ - 1);
    const int t  = threadIdx.x;
    const int lane = t & 63;
    const int wv   = t >> 6;

    __shared__ int s_n[S_];
    __shared__ float arr[S_][C_ + 1];    // stride 129: column reads conflict-free

    if (t < S_) {
        const float* out_idx = out + (size_t)B_ * NCH_ * M_ * S_;
        s_n[t] = (int)out_idx[(size_t)bm * S_ + t];
    }
    __syncthreads();

    // stage features: per sample, 64 lanes read contiguous 512 B (float2 each)
    const float* fb = ft + (size_t)b * N_ * C_;
#pragma unroll
    for (int i = 0; i < 16; ++i) {
        const int s = wv * 16 + i;
        const int n = s_n[s];
        const float2 v = *(const float2*)(fb + (size_t)n * C_ + 2 * lane);
        arr[s][2 * lane]     = v.x;
        arr[s][2 * lane + 1] = v.y;
    }

    // grouped relative xyz -> channels 0..2 (xyz is tiny, L2-resident)
    if (t < 3 * S_) {
        const int ch = t >> 6;
        const int s  = t & 63;
        const int n  = s_n[s];
        const float v = (xyz[((size_t)b * N_ + n) * 3 + ch] - new_xyz[bm * 3 + ch]) / 0.3f;
        out[(((size_t)b * NCH_ + ch) * M_ + m) * S_ + s] = v;
    }
    __syncthreads();

    // write features: lane == s, coalesced 256 B per channel
    float* ob = out + (((size_t)b * NCH_ + 3) * M_ + m) * S_ + lane;
    for (int ch = wv; ch < C_; ch += 4) {
        ob[(size_t)ch * (M_ * S_)] = arr[lane][ch];
    }
}

// ---------------- Fallback: round-1 fused kernel (if ws too small) -----------
__global__ __launch_bounds__(256) void qg_fused(
    const float* __restrict__ xyz,
    const float* __restrict__ new_xyz,
    const float* __restrict__ features,
    float* __restrict__ out)
{
    const int bm = blockIdx.x;
    const int b  = bm >> 10;
    const int m  = bm & (M_ - 1);
    const int tid = threadIdx.x;

    __shared__ int s_idx[S_];

    if (tid < 64) {
        const int lane = tid;
        const float cx = new_xyz[bm * 3 + 0];
        const float cy = new_xyz[bm * 3 + 1];
        const float cz = new_xyz[bm * 3 + 2];
        const float r2 = (float)(0.3 * 0.3);
        const float* xb = xyz + (size_t)b * N_ * 3;

        int cnt = 0;
        for (int base = 0; base < N_; base += 64) {
            const int n = base + lane;
            bool valid = false;
            if (n < N_) {
                const float dx = __fadd_rn(xb[n * 3 + 0], -cx);
                const float dy = __fadd_rn(xb[n * 3 + 1], -cy);
                const float dz = __fadd_rn(xb[n * 3 + 2], -cz);
                const float d2 = __fadd_rn(
                    __fadd_rn(__fmul_rn(dx, dx), __fmul_rn(dy, dy)),
                    __fmul_rn(dz, dz));
                valid = d2 < r2;
            }
            const unsigned long long mk = __ballot(valid);
            if (valid) {
                const int pos = cnt + __popcll(mk & ((1ull << lane) - 1ull));
                if (pos < S_) s_idx[pos] = n;
            }
            cnt += __popcll(mk);
            if (cnt >= S_) break;
        }
        const int c = cnt < S_ ? cnt : S_;
        const int first = (c > 0) ? s_idx[0] : 0;
        if (lane >= c) s_idx[lane] = first;

        float* out_idx = out + (size_t)B_ * NCH_ * M_ * S_;
        out_idx[(size_t)bm * S_ + lane] = (float)s_idx[lane];
    }
    __syncthreads();

    if (tid < 3 * S_) {
        const int ch = tid >> 6;
        const int s  = tid & 63;
        const int n  = s_idx[s];
        const float v = (xyz[((size_t)b * N_ + n) * 3 + ch] - new_xyz[bm * 3 + ch]) / 0.3f;
        out[(((size_t)b * NCH_ + ch) * M_ + m) * S_ + s] = v;
    }

    const int s  = tid & 63;
    const int cq = tid >> 6;
    const int n  = s_idx[s];
    const float* fb = features + (size_t)b * C_ * N_;
    float* ob = out + (((size_t)b * NCH_ + 3) * M_ + m) * S_ + s;
    for (int ch = cq; ch < C_; ch += 4) {
        ob[(size_t)ch * (M_ * S_)] = fb[(size_t)ch * N_ + n];
    }
}

extern "C" void kernel_launch(void* const* d_in, const int* in_sizes, int n_in,
                              void* d_out, int out_size, void* d_ws, size_t ws_size,
                              hipStream_t stream) {
    const float* xyz      = (const float*)d_in[0];
    const float* new_xyz  = (const float*)d_in[1];
    // d_in[2] = batch_distances, d_in[3] = inds : acceleration hints only, unused
    const float* features = (const float*)d_in[4];
    float* out = (float*)d_out;

    const size_t need = (size_t)B_ * N_ * C_ * sizeof(float);  // 81.92 MB
    if (ws_size < need) {
        qg_fused<<<B_ * M_, 256, 0, stream>>>(xyz, new_xyz, features, out);
        return;
    }
    float* ft = (float*)d_ws;

    query_kernel<<<(B_ * M_) / 4, 256, 0, stream>>>(xyz, new_xyz, out);
    transpose_kernel<<<dim3(N_ / 32, C_ / 32, B_), dim3(32, 8), 0, stream>>>(features, ft);
    gather_kernel<<<B_ * M_, 256, 0, stream>>>(xyz, new_xyz, ft, out);
}

// Round 3
// 209.047 us; speedup vs baseline: 2.4282x; 1.1646x over previous
//
#include <hip/hip_runtime.h>

#define B_ 8
#define N_ 20000
#define M_ 1024
#define C_ 128
#define S_ 64
#define NCH_ 131   // 3 + C

// ---- K1: ball query -> idx (float out + int ws) + grouped relative xyz -----
__global__ __launch_bounds__(256) void query_kernel(
    const float* __restrict__ xyz,       // (B, N, 3)
    const float* __restrict__ new_xyz,   // (B, M, 3)
    float* __restrict__ out,
    int* __restrict__ iws)               // (B, M, S) int scratch
{
    const int wid  = threadIdx.x >> 6;
    const int lane = threadIdx.x & 63;
    const int bm   = blockIdx.x * 4 + wid;
    const int b    = bm >> 10;
    const int m    = bm & (M_ - 1);

    __shared__ int s_idx[4][S_];

    const float cx = new_xyz[bm * 3 + 0];
    const float cy = new_xyz[bm * 3 + 1];
    const float cz = new_xyz[bm * 3 + 2];
    const float r2 = (float)(0.3 * 0.3);
    const float* xb = xyz + (size_t)b * N_ * 3;

    int cnt = 0;
    for (int base = 0; base < N_; base += 64) {
        const int n = base + lane;
        bool valid = false;
        if (n < N_) {
            // match numpy f32 rounding exactly: no FMA contraction
            const float dx = __fadd_rn(xb[n * 3 + 0], -cx);
            const float dy = __fadd_rn(xb[n * 3 + 1], -cy);
            const float dz = __fadd_rn(xb[n * 3 + 2], -cz);
            const float d2 = __fadd_rn(
                __fadd_rn(__fmul_rn(dx, dx), __fmul_rn(dy, dy)),
                __fmul_rn(dz, dz));
            valid = d2 < r2;
        }
        const unsigned long long mk = __ballot(valid);
        if (valid) {
            const int pos = cnt + __popcll(mk & ((1ull << lane) - 1ull));
            if (pos < S_) s_idx[wid][pos] = n;
        }
        cnt += __popcll(mk);
        if (cnt >= S_) break;   // wave-uniform
    }
    const int c = cnt < S_ ? cnt : S_;
    const int first = (c > 0) ? s_idx[wid][0] : 0;
    if (lane >= c) s_idx[wid][lane] = first;

    const int n = s_idx[wid][lane];

    // idx outputs
    float* out_idx = out + (size_t)B_ * NCH_ * M_ * S_;
    out_idx[(size_t)bm * S_ + lane] = (float)n;
    iws[(size_t)bm * S_ + lane] = n;

    // grouped relative xyz -> channels 0..2 (xyz L2-hot; writes coalesced 256B)
    const float px = xb[n * 3 + 0];
    const float py = xb[n * 3 + 1];
    const float pz = xb[n * 3 + 2];
    out[(((size_t)b * NCH_ + 0) * M_ + m) * S_ + lane] = (px - cx) / 0.3f;
    out[(((size_t)b * NCH_ + 1) * M_ + m) * S_ + lane] = (py - cy) / 0.3f;
    out[(((size_t)b * NCH_ + 2) * M_ + m) * S_ + lane] = (pz - cz) / 0.3f;
}

// ---- K2: per (b,ch) block -- stage 80KB channel slice in LDS, gather-write -
__global__ __launch_bounds__(256) void group_feat_kernel(
    const float* __restrict__ features,  // (B, C, N)
    const int* __restrict__ iws,         // (B, M, S)
    float* __restrict__ out)
{
    // b = blockIdx & 7: round-robin dispatch pins each batch to one XCD,
    // keeping that batch's idx slice (256 KB) L2-resident.
    const int b  = blockIdx.x & 7;
    const int ch = blockIdx.x >> 3;

    __shared__ float slice[N_];          // 80000 B (gfx950: >64KB LDS ok)

    const float* fb = features + ((size_t)b * C_ + ch) * N_;
    // N_ = 20000 = 5000 float4; base offset is 80000B-aligned
    const float4* fb4 = (const float4*)fb;
    float4* sl4 = (float4*)slice;
    for (int i = threadIdx.x; i < N_ / 4; i += 256)
        sl4[i] = fb4[i];
    __syncthreads();

    const int* ib = iws + (size_t)b * M_ * S_;
    float* ob = out + ((size_t)b * NCH_ + 3 + ch) * (size_t)(M_ * S_);
#pragma unroll 8
    for (int e = threadIdx.x; e < M_ * S_; e += 256)
        ob[e] = slice[ib[e]];
}

// ---- Fallback: round-1 fused kernel (if ws too small) ----------------------
__global__ __launch_bounds__(256) void qg_fused(
    const float* __restrict__ xyz,
    const float* __restrict__ new_xyz,
    const float* __restrict__ features,
    float* __restrict__ out)
{
    const int bm = blockIdx.x;
    const int b  = bm >> 10;
    const int m  = bm & (M_ - 1);
    const int tid = threadIdx.x;

    __shared__ int s_idx[S_];

    if (tid < 64) {
        const int lane = tid;
        const float cx = new_xyz[bm * 3 + 0];
        const float cy = new_xyz[bm * 3 + 1];
        const float cz = new_xyz[bm * 3 + 2];
        const float r2 = (float)(0.3 * 0.3);
        const float* xb = xyz + (size_t)b * N_ * 3;

        int cnt = 0;
        for (int base = 0; base < N_; base += 64) {
            const int n = base + lane;
            bool valid = false;
            if (n < N_) {
                const float dx = __fadd_rn(xb[n * 3 + 0], -cx);
                const float dy = __fadd_rn(xb[n * 3 + 1], -cy);
                const float dz = __fadd_rn(xb[n * 3 + 2], -cz);
                const float d2 = __fadd_rn(
                    __fadd_rn(__fmul_rn(dx, dx), __fmul_rn(dy, dy)),
                    __fmul_rn(dz, dz));
                valid = d2 < r2;
            }
            const unsigned long long mk = __ballot(valid);
            if (valid) {
                const int pos = cnt + __popcll(mk & ((1ull << lane) - 1ull));
                if (pos < S_) s_idx[pos] = n;
            }
            cnt += __popcll(mk);
            if (cnt >= S_) break;
        }
        const int c = cnt < S_ ? cnt : S_;
        const int first = (c > 0) ? s_idx[0] : 0;
        if (lane >= c) s_idx[lane] = first;

        float* out_idx = out + (size_t)B_ * NCH_ * M_ * S_;
        out_idx[(size_t)bm * S_ + lane] = (float)s_idx[lane];
    }
    __syncthreads();

    if (tid < 3 * S_) {
        const int ch = tid >> 6;
        const int s  = tid & 63;
        const int n  = s_idx[s];
        const float v = (xyz[((size_t)b * N_ + n) * 3 + ch] - new_xyz[bm * 3 + ch]) / 0.3f;
        out[(((size_t)b * NCH_ + ch) * M_ + m) * S_ + s] = v;
    }

    const int s  = tid & 63;
    const int cq = tid >> 6;
    const int n  = s_idx[s];
    const float* fb = features + (size_t)b * C_ * N_;
    float* ob = out + (((size_t)b * NCH_ + 3) * M_ + m) * S_ + s;
    for (int ch = cq; ch < C_; ch += 4) {
        ob[(size_t)ch * (M_ * S_)] = fb[(size_t)ch * N_ + n];
    }
}

extern "C" void kernel_launch(void* const* d_in, const int* in_sizes, int n_in,
                              void* d_out, int out_size, void* d_ws, size_t ws_size,
                              hipStream_t stream) {
    const float* xyz      = (const float*)d_in[0];
    const float* new_xyz  = (const float*)d_in[1];
    // d_in[2] = batch_distances, d_in[3] = inds : acceleration hints only, unused
    const float* features = (const float*)d_in[4];
    float* out = (float*)d_out;

    const size_t need = (size_t)B_ * M_ * S_ * sizeof(int);  // 2 MB
    if (ws_size < need) {
        qg_fused<<<B_ * M_, 256, 0, stream>>>(xyz, new_xyz, features, out);
        return;
    }
    int* iws = (int*)d_ws;

    query_kernel<<<(B_ * M_) / 4, 256, 0, stream>>>(xyz, new_xyz, out, iws);
    group_feat_kernel<<<B_ * C_, 256, 0, stream>>>(features, iws, out);
}

// Round 4
// 165.839 us; speedup vs baseline: 3.0608x; 1.2605x over previous
//
#include <hip/hip_runtime.h>

#define B_ 8
#define N_ 20000
#define M_ 1024
#define C_ 128
#define S_ 64
#define NCH_ 131   // 3 + C

// ---- K1: ball query (512 pts/iter/wave) + idx + grouped relative xyz -------
__global__ __launch_bounds__(256) void query_kernel(
    const float* __restrict__ xyz,       // (B, N, 3)
    const float* __restrict__ new_xyz,   // (B, M, 3)
    float* __restrict__ out,
    int* __restrict__ iws)               // (B, M, S) int scratch
{
    const int wid  = threadIdx.x >> 6;
    const int lane = threadIdx.x & 63;
    const int bm   = blockIdx.x * 4 + wid;
    const int b    = bm >> 10;
    const int m    = bm & (M_ - 1);

    __shared__ int s_idx[4][S_];

    const float cx = new_xyz[bm * 3 + 0];
    const float cy = new_xyz[bm * 3 + 1];
    const float cz = new_xyz[bm * 3 + 2];
    const float r2 = (float)(0.3 * 0.3);
    const float* xb = xyz + (size_t)b * N_ * 3;
    const unsigned long long below = (1ull << lane) - 1ull;

    int cnt = 0;
    for (int base = 0; base < N_ && cnt < S_; base += 512) {
        const int n0 = base + 8 * lane;          // 8 consecutive points per lane
        const bool inb = (n0 < N_);              // N_%8==0 -> all 8 in-range iff inb

        float f[24];
        if (inb) {
            // 12*n0 bytes, n0%8==0 -> 16B aligned; 6 independent float4 loads
            const float4* p4 = (const float4*)(xb + (size_t)n0 * 3);
#pragma unroll
            for (int q = 0; q < 6; ++q) {
                const float4 v = p4[q];
                f[4 * q + 0] = v.x; f[4 * q + 1] = v.y;
                f[4 * q + 2] = v.z; f[4 * q + 3] = v.w;
            }
        }

        unsigned vbits = 0;
        if (inb) {
#pragma unroll
            for (int j = 0; j < 8; ++j) {
                // match numpy f32 rounding exactly: no FMA contraction
                const float dx = __fadd_rn(f[3 * j + 0], -cx);
                const float dy = __fadd_rn(f[3 * j + 1], -cy);
                const float dz = __fadd_rn(f[3 * j + 2], -cz);
                const float d2 = __fadd_rn(
                    __fadd_rn(__fmul_rn(dx, dx), __fmul_rn(dy, dy)),
                    __fmul_rn(dz, dz));
                if (d2 < r2) vbits |= (1u << j);
            }
        }

        // wave-uniform masks (SGPR pairs), lane-major point ordering
        unsigned long long mk[8];
#pragma unroll
        for (int j = 0; j < 8; ++j) mk[j] = __ballot((vbits >> j) & 1u);

        int pre = 0, tot = 0;
#pragma unroll
        for (int j = 0; j < 8; ++j) {
            pre += __popcll(mk[j] & below);      // valid pts in lanes < lane
            tot += __popcll(mk[j]);              // valid pts this tile
        }

        int pos = cnt + pre;
#pragma unroll
        for (int j = 0; j < 8; ++j) {
            if (vbits & (1u << j)) {
                if (pos < S_) s_idx[wid][pos] = n0 + j;
                ++pos;
            }
        }
        cnt += tot;
    }

    const int c = cnt < S_ ? cnt : S_;
    const int first = (c > 0) ? s_idx[wid][0] : 0;
    if (lane >= c) s_idx[wid][lane] = first;

    const int n = s_idx[wid][lane];

    // idx outputs (float copy in d_out, int copy for K2)
    float* out_idx = out + (size_t)B_ * NCH_ * M_ * S_;
    out_idx[(size_t)bm * S_ + lane] = (float)n;
    iws[(size_t)bm * S_ + lane] = n;

    // grouped relative xyz -> channels 0..2 (xyz L2-hot; writes coalesced 256B)
    const float px = xb[n * 3 + 0];
    const float py = xb[n * 3 + 1];
    const float pz = xb[n * 3 + 2];
    out[(((size_t)b * NCH_ + 0) * M_ + m) * S_ + lane] = (px - cx) / 0.3f;
    out[(((size_t)b * NCH_ + 1) * M_ + m) * S_ + lane] = (py - cy) / 0.3f;
    out[(((size_t)b * NCH_ + 2) * M_ + m) * S_ + lane] = (pz - cz) / 0.3f;
}

// ---- K2: per (b,ch) block -- stage 80KB channel slice in LDS, gather-write -
__global__ __launch_bounds__(256) void group_feat_kernel(
    const float* __restrict__ features,  // (B, C, N)
    const int* __restrict__ iws,         // (B, M, S)
    float* __restrict__ out)
{
    // b = blockIdx & 7: round-robin dispatch pins each batch to one XCD,
    // keeping that batch's idx slice (256 KB) L2-resident.
    const int b  = blockIdx.x & 7;
    const int ch = blockIdx.x >> 3;

    __shared__ float slice[N_];          // 80000 B (gfx950: >64KB LDS ok)

    const float* fb = features + ((size_t)b * C_ + ch) * N_;
    const float4* fb4 = (const float4*)fb;
    float4* sl4 = (float4*)slice;
    for (int i = threadIdx.x; i < N_ / 4; i += 256)
        sl4[i] = fb4[i];
    __syncthreads();

    const int* ib = iws + (size_t)b * M_ * S_;
    float* ob = out + ((size_t)b * NCH_ + 3 + ch) * (size_t)(M_ * S_);
#pragma unroll 8
    for (int e = threadIdx.x; e < M_ * S_; e += 256)
        ob[e] = slice[ib[e]];
}

// ---- Fallback: round-1 fused kernel (if ws too small) ----------------------
__global__ __launch_bounds__(256) void qg_fused(
    const float* __restrict__ xyz,
    const float* __restrict__ new_xyz,
    const float* __restrict__ features,
    float* __restrict__ out)
{
    const int bm = blockIdx.x;
    const int b  = bm >> 10;
    const int m  = bm & (M_ - 1);
    const int tid = threadIdx.x;

    __shared__ int s_idx[S_];

    if (tid < 64) {
        const int lane = tid;
        const float cx = new_xyz[bm * 3 + 0];
        const float cy = new_xyz[bm * 3 + 1];
        const float cz = new_xyz[bm * 3 + 2];
        const float r2 = (float)(0.3 * 0.3);
        const float* xb = xyz + (size_t)b * N_ * 3;

        int cnt = 0;
        for (int base = 0; base < N_; base += 64) {
            const int n = base + lane;
            bool valid = false;
            if (n < N_) {
                const float dx = __fadd_rn(xb[n * 3 + 0], -cx);
                const float dy = __fadd_rn(xb[n * 3 + 1], -cy);
                const float dz = __fadd_rn(xb[n * 3 + 2], -cz);
                const float d2 = __fadd_rn(
                    __fadd_rn(__fmul_rn(dx, dx), __fmul_rn(dy, dy)),
                    __fmul_rn(dz, dz));
                valid = d2 < r2;
            }
            const unsigned long long mk = __ballot(valid);
            if (valid) {
                const int pos = cnt + __popcll(mk & ((1ull << lane) - 1ull));
                if (pos < S_) s_idx[pos] = n;
            }
            cnt += __popcll(mk);
            if (cnt >= S_) break;
        }
        const int c = cnt < S_ ? cnt : S_;
        const int first = (c > 0) ? s_idx[0] : 0;
        if (lane >= c) s_idx[lane] = first;

        float* out_idx = out + (size_t)B_ * NCH_ * M_ * S_;
        out_idx[(size_t)bm * S_ + lane] = (float)s_idx[lane];
    }
    __syncthreads();

    if (tid < 3 * S_) {
        const int ch = tid >> 6;
        const int s  = tid & 63;
        const int n  = s_idx[s];
        const float v = (xyz[((size_t)b * N_ + n) * 3 + ch] - new_xyz[bm * 3 + ch]) / 0.3f;
        out[(((size_t)b * NCH_ + ch) * M_ + m) * S_ + s] = v;
    }

    const int s  = tid & 63;
    const int cq = tid >> 6;
    const int n  = s_idx[s];
    const float* fb = features + (size_t)b * C_ * N_;
    float* ob = out + (((size_t)b * NCH_ + 3) * M_ + m) * S_ + s;
    for (int ch = cq; ch < C_; ch += 4) {
        ob[(size_t)ch * (M_ * S_)] = fb[(size_t)ch * N_ + n];
    }
}

extern "C" void kernel_launch(void* const* d_in, const int* in_sizes, int n_in,
                              void* d_out, int out_size, void* d_ws, size_t ws_size,
                              hipStream_t stream) {
    const float* xyz      = (const float*)d_in[0];
    const float* new_xyz  = (const float*)d_in[1];
    // d_in[2] = batch_distances, d_in[3] = inds : acceleration hints only, unused
    const float* features = (const float*)d_in[4];
    float* out = (float*)d_out;

    const size_t need = (size_t)B_ * M_ * S_ * sizeof(int);  // 2 MB
    if (ws_size < need) {
        qg_fused<<<B_ * M_, 256, 0, stream>>>(xyz, new_xyz, features, out);
        return;
    }
    int* iws = (int*)d_ws;

    query_kernel<<<(B_ * M_) / 4, 256, 0, stream>>>(xyz, new_xyz, out, iws);
    group_feat_kernel<<<B_ * C_, 256, 0, stream>>>(features, iws, out);
}

// Round 6
// 135.048 us; speedup vs baseline: 3.7587x; 1.2280x over previous
//
#include <hip/hip_runtime.h>

#define B_ 8
#define N_ 20000
#define M_ 1024
#define C_ 128
#define S_ 64
#define NCH_ 131   // 3 + C
#define TILE_ 512  // points per wave-iteration (8 per lane)

typedef float  vf4 __attribute__((ext_vector_type(4)));  // nontemporal-compatible 16B

// ---- K1: ball query, 2-deep software-pipelined 512-pt tiles ----------------
__global__ __launch_bounds__(256) void query_kernel(
    const float* __restrict__ xyz,       // (B, N, 3)
    const float* __restrict__ new_xyz,   // (B, M, 3)
    float* __restrict__ out,
    int* __restrict__ iws)               // (B, M, S) int scratch
{
    const int wid  = threadIdx.x >> 6;
    const int lane = threadIdx.x & 63;
    const int bm   = blockIdx.x * 4 + wid;
    const int b    = bm >> 10;
    const int m    = bm & (M_ - 1);

    __shared__ int s_idx[4][S_];

    const float cx = new_xyz[bm * 3 + 0];
    const float cy = new_xyz[bm * 3 + 1];
    const float cz = new_xyz[bm * 3 + 2];
    const float r2 = (float)(0.3 * 0.3);
    const float* xb = xyz + (size_t)b * N_ * 3;
    const unsigned long long below = (1ull << lane) - 1ull;

// load one 512-pt tile into 24 regs (6 independent float4 loads, 16B aligned)
#define LOAD_TILE(F, INB, NB, BASE) do {                                      \
    NB = (BASE) + 8 * lane;                                                   \
    INB = (NB < N_);   /* N_%8==0: all 8 of this lane in-range iff INB */     \
    if (INB) {                                                                \
        const float4* p4_ = (const float4*)(xb + (size_t)NB * 3);             \
        _Pragma("unroll")                                                     \
        for (int q = 0; q < 6; ++q) {                                         \
            const float4 v_ = p4_[q];                                         \
            F[4*q+0] = v_.x; F[4*q+1] = v_.y; F[4*q+2] = v_.z; F[4*q+3] = v_.w; \
        }                                                                     \
    } } while (0)

// process one tile: exact numpy f32 rounding (no FMA contraction)
#define PROC_TILE(F, INB, NB) do {                                            \
    unsigned vbits = 0;                                                       \
    if (INB) {                                                                \
        _Pragma("unroll")                                                     \
        for (int j = 0; j < 8; ++j) {                                         \
            const float dx = __fadd_rn(F[3*j+0], -cx);                        \
            const float dy = __fadd_rn(F[3*j+1], -cy);                        \
            const float dz = __fadd_rn(F[3*j+2], -cz);                        \
            const float d2 = __fadd_rn(                                       \
                __fadd_rn(__fmul_rn(dx, dx), __fmul_rn(dy, dy)),              \
                __fmul_rn(dz, dz));                                           \
            if (d2 < r2) vbits |= (1u << j);                                  \
        }                                                                     \
    }                                                                         \
    int pre = 0, tot = 0;                                                     \
    _Pragma("unroll")                                                         \
    for (int j = 0; j < 8; ++j) {                                             \
        const unsigned long long mk = __ballot((vbits >> j) & 1u);            \
        pre += __popcll(mk & below);                                          \
        tot += __popcll(mk);                                                  \
    }                                                                         \
    int pos = cnt + pre;                                                      \
    _Pragma("unroll")                                                         \
    for (int j = 0; j < 8; ++j) {                                             \
        if (vbits & (1u << j)) {                                              \
            if (pos < S_) s_idx[wid][pos] = NB + j;                           \
            ++pos;                                                            \
        }                                                                     \
    }                                                                         \
    cnt += tot; } while (0)

    int cnt = 0;
    float fA[24], fB[24];
    bool inbA = false, inbB = false;
    int nA = 0, nB = 0;

    LOAD_TILE(fA, inbA, nA, 0);
    int base = 0;
    for (;;) {
        // stage 1: prefetch next tile into B, process A
        {
            const int nxt = base + TILE_;
            const bool have = (nxt < N_);
            if (have) LOAD_TILE(fB, inbB, nB, nxt);
            PROC_TILE(fA, inbA, nA);
            base = nxt;
            if (cnt >= S_ || !have) break;
        }
        // stage 2: prefetch next tile into A, process B
        {
            const int nxt = base + TILE_;
            const bool have = (nxt < N_);
            if (have) LOAD_TILE(fA, inbA, nA, nxt);
            PROC_TILE(fB, inbB, nB);
            base = nxt;
            if (cnt >= S_ || !have) break;
        }
    }
#undef LOAD_TILE
#undef PROC_TILE

    const int c = cnt < S_ ? cnt : S_;
    const int first = (c > 0) ? s_idx[wid][0] : 0;
    if (lane >= c) s_idx[wid][lane] = first;

    const int n = s_idx[wid][lane];

    // idx outputs (float copy in d_out, int copy for K2 -- keep iws L2-cached)
    float* out_idx = out + (size_t)B_ * NCH_ * M_ * S_;
    __builtin_nontemporal_store((float)n, &out_idx[(size_t)bm * S_ + lane]);
    iws[(size_t)bm * S_ + lane] = n;

    // grouped relative xyz -> channels 0..2 (xyz L2-hot; writes coalesced 256B)
    const float px = xb[n * 3 + 0];
    const float py = xb[n * 3 + 1];
    const float pz = xb[n * 3 + 2];
    __builtin_nontemporal_store((px - cx) / 0.3f,
        &out[(((size_t)b * NCH_ + 0) * M_ + m) * S_ + lane]);
    __builtin_nontemporal_store((py - cy) / 0.3f,
        &out[(((size_t)b * NCH_ + 1) * M_ + m) * S_ + lane]);
    __builtin_nontemporal_store((pz - cz) / 0.3f,
        &out[(((size_t)b * NCH_ + 2) * M_ + m) * S_ + lane]);
}

// ---- K2: per (b,ch) block -- stage 80KB channel slice in LDS, gather-write -
__global__ __launch_bounds__(256) void group_feat_kernel(
    const float* __restrict__ features,  // (B, C, N)
    const int* __restrict__ iws,         // (B, M, S)
    float* __restrict__ out)
{
    // b = blockIdx & 7: round-robin dispatch pins each batch to one XCD,
    // keeping that batch's idx slice (256 KB) L2-resident.
    const int b  = blockIdx.x & 7;
    const int ch = blockIdx.x >> 3;

    __shared__ float slice[N_];          // 80000 B (gfx950: >64KB LDS ok)

    const float* fb = features + ((size_t)b * C_ + ch) * N_;
    const vf4* fb4 = (const vf4*)fb;
    vf4* sl4 = (vf4*)slice;
    for (int i = threadIdx.x; i < N_ / 4; i += 256)
        sl4[i] = __builtin_nontemporal_load(&fb4[i]);  // read-once stream
    __syncthreads();

    const int* ib = iws + (size_t)b * M_ * S_;
    float* ob = out + ((size_t)b * NCH_ + 3 + ch) * (size_t)(M_ * S_);
    // 4 elems/thread: int4 idx load + float4 nontemporal store (streamed out)
    for (int e = threadIdx.x * 4; e < M_ * S_; e += 256 * 4) {
        const int4 ii = *(const int4*)(ib + e);
        vf4 w;
        w.x = slice[ii.x]; w.y = slice[ii.y];
        w.z = slice[ii.z]; w.w = slice[ii.w];
        __builtin_nontemporal_store(w, (vf4*)(ob + e));
    }
}

// ---- Fallback: round-1 fused kernel (if ws too small) ----------------------
__global__ __launch_bounds__(256) void qg_fused(
    const float* __restrict__ xyz,
    const float* __restrict__ new_xyz,
    const float* __restrict__ features,
    float* __restrict__ out)
{
    const int bm = blockIdx.x;
    const int b  = bm >> 10;
    const int m  = bm & (M_ - 1);
    const int tid = threadIdx.x;

    __shared__ int s_idx[S_];

    if (tid < 64) {
        const int lane = tid;
        const float cx = new_xyz[bm * 3 + 0];
        const float cy = new_xyz[bm * 3 + 1];
        const float cz = new_xyz[bm * 3 + 2];
        const float r2 = (float)(0.3 * 0.3);
        const float* xb = xyz + (size_t)b * N_ * 3;

        int cnt = 0;
        for (int base = 0; base < N_; base += 64) {
            const int n = base + lane;
            bool valid = false;
            if (n < N_) {
                const float dx = __fadd_rn(xb[n * 3 + 0], -cx);
                const float dy = __fadd_rn(xb[n * 3 + 1], -cy);
                const float dz = __fadd_rn(xb[n * 3 + 2], -cz);
                const float d2 = __fadd_rn(
                    __fadd_rn(__fmul_rn(dx, dx), __fmul_rn(dy, dy)),
                    __fmul_rn(dz, dz));
                valid = d2 < r2;
            }
            const unsigned long long mk = __ballot(valid);
            if (valid) {
                const int pos = cnt + __popcll(mk & ((1ull << lane) - 1ull));
                if (pos < S_) s_idx[pos] = n;
            }
            cnt += __popcll(mk);
            if (cnt >= S_) break;
        }
        const int c = cnt < S_ ? cnt : S_;
        const int first = (c > 0) ? s_idx[0] : 0;
        if (lane >= c) s_idx[lane] = first;

        float* out_idx = out + (size_t)B_ * NCH_ * M_ * S_;
        out_idx[(size_t)bm * S_ + lane] = (float)s_idx[lane];
    }
    __syncthreads();

    if (tid < 3 * S_) {
        const int ch = tid >> 6;
        const int s  = tid & 63;
        const int n  = s_idx[s];
        const float v = (xyz[((size_t)b * N_ + n) * 3 + ch] - new_xyz[bm * 3 + ch]) / 0.3f;
        out[(((size_t)b * NCH_ + ch) * M_ + m) * S_ + s] = v;
    }

    const int s  = tid & 63;
    const int cq = tid >> 6;
    const int n  = s_idx[s];
    const float* fb = features + (size_t)b * C_ * N_;
    float* ob = out + (((size_t)b * NCH_ + 3) * M_ + m) * S_ + s;
    for (int ch = cq; ch < C_; ch += 4) {
        ob[(size_t)ch * (M_ * S_)] = fb[(size_t)ch * N_ + n];
    }
}

extern "C" void kernel_launch(void* const* d_in, const int* in_sizes, int n_in,
                              void* d_out, int out_size, void* d_ws, size_t ws_size,
                              hipStream_t stream) {
    const float* xyz      = (const float*)d_in[0];
    const float* new_xyz  = (const float*)d_in[1];
    // d_in[2] = batch_distances, d_in[3] = inds : acceleration hints only, unused
    const float* features = (const float*)d_in[4];
    float* out = (float*)d_out;

    const size_t need = (size_t)B_ * M_ * S_ * sizeof(int);  // 2 MB
    if (ws_size < need) {
        qg_fused<<<B_ * M_, 256, 0, stream>>>(xyz, new_xyz, features, out);
        return;
    }
    int* iws = (int*)d_ws;

    query_kernel<<<(B_ * M_) / 4, 256, 0, stream>>>(xyz, new_xyz, out, iws);
    group_feat_kernel<<<B_ * C_, 256, 0, stream>>>(features, iws, out);
}